// Round 3
// baseline (542.251 us; speedup 1.0000x reference)
//
#include <hip/hip_runtime.h>
#include <hip/hip_bf16.h>

#define HDIM 128
#define RS 136    // hbf row stride in bf16 (128 + 8 pad)
#define XS 264    // X row stride in bf16 (256 + 8 pad)
#define SPB 8     // sessions per block

typedef __attribute__((ext_vector_type(8))) short short8;
typedef __attribute__((ext_vector_type(4))) float floatv4;

static __device__ __forceinline__ unsigned short f2bf(float f) {
  union { float f; unsigned u; } x; x.f = f;
  unsigned r = x.u + 0x7fffu + ((x.u >> 16) & 1u);  // RNE
  return (unsigned short)(r >> 16);
}
static __device__ __forceinline__ float blo(unsigned u) { return __uint_as_float(u << 16); }
static __device__ __forceinline__ float bhi(unsigned u) { return __uint_as_float(u & 0xffff0000u); }

// Merged prep: block 0 scans seq_len -> offs; blocks 1..128 convert weights to bf16.
__global__ void prep_kernel(const int* __restrict__ seq, int* __restrict__ offs, int B,
                            const float* __restrict__ W1, const float* __restrict__ W2,
                            const float* __restrict__ W3,
                            unsigned short* __restrict__ w1b, unsigned short* __restrict__ w2b,
                            unsigned short* __restrict__ w3b) {
  if (blockIdx.x == 0) {
    __shared__ int part[256];
    int tid = threadIdx.x;
    int chunk = (B + 255) >> 8;
    int beg = tid * chunk, end = min(beg + chunk, B);
    int s = 0;
    for (int i = beg; i < end; ++i) s += seq[i];
    part[tid] = s;
    __syncthreads();
    for (int d = 1; d < 256; d <<= 1) {
      int v = (tid >= d) ? part[tid - d] : 0;
      __syncthreads();
      part[tid] += v;
      __syncthreads();
    }
    int run = (tid == 0) ? 0 : part[tid - 1];
    for (int i = beg; i < end; ++i) { offs[i] = run; run += seq[i]; }
  } else {
    int i = (blockIdx.x - 1) * 256 + threadIdx.x;
    if (i < 16384) { w1b[i] = f2bf(W1[i]); w2b[i] = f2bf(W2[i]); }
    if (i < 32768) { w3b[i] = f2bf(W3[i]); }
  }
}

// One block per 8 sessions. 256 threads = 4 waves.
__global__ __launch_bounds__(256, 3) void session_kernel(
    const float* __restrict__ intra, const float* __restrict__ inter,
    const unsigned short* __restrict__ w1b, const float* __restrict__ b1,
    const unsigned short* __restrict__ w2b, const float* __restrict__ b2,
    const float* __restrict__ qw, const float* __restrict__ qb,
    const unsigned short* __restrict__ w3b, const float* __restrict__ b3,
    const int* __restrict__ seq, const int* __restrict__ offs,
    float* __restrict__ out, int B) {
  __shared__ unsigned short hbf[64 * RS];   // 17408 B: current session's hidden tile (bf16)
  __shared__ unsigned short X[16 * XS];     // 8448 B: rows 0..7 = [vn | sg] per session (bf16)
  __shared__ float cbuf[SPB][HDIM];         // 4096 B: W1@vn + b1 + b2 per session
  __shared__ float alphaPart[4][64];        // 1024 B: per-wave alpha partials
  __shared__ float sgpart[4][HDIM];         // 2048 B: per-wave s_g partials

  const int tid = threadIdx.x;
  const int lane = tid & 63, wid = tid >> 6;
  const int quad = lane >> 4, lcol = lane & 15;
  const int n0 = (wid << 5) + lcol, n1 = n0 + 16;  // this lane's two output columns
  const int sid0 = blockIdx.x * SPB;

  // ---- Prologue: issue session-0 staging loads ASAP, then gather/pre-pass ----
  int n_nxt = 0, start_nxt = 0;
  if (sid0 < B) { n_nxt = seq[sid0]; start_nxt = offs[sid0]; }

  float4 ra[8], rb[8];
  {
    const float4* pa = (const float4*)(intra + (size_t)start_nxt * HDIM);
    const float4* pb = (const float4*)(inter + (size_t)start_nxt * HDIM);
    int nc = (n_nxt > 64) ? 64 : n_nxt;
    #pragma unroll
    for (int it = 0; it < 8; ++it) {
      int idx = (it << 8) + tid;
      int t = idx >> 5;
      float4 va = {0.f, 0.f, 0.f, 0.f}, vb = {0.f, 0.f, 0.f, 0.f};
      if (t < nc) { va = pa[idx]; vb = pb[idx]; }
      ra[it] = va; rb[it] = vb;
    }
  }
  // scalar prefetch for session 1
  if (1 < SPB && sid0 + 1 < B) { n_nxt = seq[sid0 + 1]; start_nxt = offs[sid0 + 1]; }
  else { n_nxt = 0; start_nxt = 0; }

  // W2 B-fragments resident in registers across all sessions (B[k][n] = W2[n][k]).
  short8 w2f[2][4];
  #pragma unroll
  for (int nt = 0; nt < 2; ++nt) {
    int nn = n0 + (nt << 4);
    #pragma unroll
    for (int kt = 0; kt < 4; ++kt)
      w2f[nt][kt] = *(const short8*)(w2b + nn * HDIM + (kt << 5) + (quad << 3));
  }
  const float q0 = qw[n0], q1 = qw[n1];
  const float sq = qb[0];

  // Gather v_n for 8 sessions -> X rows 0..7, cols 0..127 (bf16).
  #pragma unroll
  for (int it = 0; it < 4; ++it) {
    int s = (it << 1) + (tid >> 7);
    int col = tid & 127;
    int sid = sid0 + s;
    int ns = 0, st = 0;
    if (sid < B) { ns = seq[sid]; st = offs[sid]; }
    float v = 0.f;
    if (ns > 0) {
      size_t base = (size_t)(st + ns - 1) * HDIM + col;
      v = fmaxf(intra[base], inter[base]);
    }
    X[s * XS + col] = f2bf(v);
  }
  __syncthreads();  // X vn-half ready

  // Batched W1 pre-pass: C = Vn @ W1^T + b1 + b2 for all 8 sessions (16x128x128 tile).
  {
    floatv4 p0 = {0.f, 0.f, 0.f, 0.f}, p1 = {0.f, 0.f, 0.f, 0.f};
    #pragma unroll
    for (int kt = 0; kt < 4; ++kt) {
      short8 af = *(const short8*)&X[lcol * XS + (kt << 5) + (quad << 3)];
      short8 bf0 = *(const short8*)(w1b + n0 * HDIM + (kt << 5) + (quad << 3));
      short8 bf1 = *(const short8*)(w1b + n1 * HDIM + (kt << 5) + (quad << 3));
      p0 = __builtin_amdgcn_mfma_f32_16x16x32_bf16(af, bf0, p0, 0, 0, 0);
      p1 = __builtin_amdgcn_mfma_f32_16x16x32_bf16(af, bf1, p1, 0, 0, 0);
    }
    if (quad < 2) {
      float bb0 = b1[n0] + b2[n0], bb1 = b1[n1] + b2[n1];
      #pragma unroll
      for (int r = 0; r < 4; ++r) {
        int m = (quad << 2) + r;   // session index 0..7
        cbuf[m][n0] = p0[r] + bb0;
        cbuf[m][n1] = p1[r] + bb1;
      }
    }
  }
  __syncthreads();  // cbuf ready

  // ---- Main session loop (software-pipelined staging) ----
  #pragma unroll 1
  for (int s = 0; s < SPB; ++s) {
    // Convert + store staged regs (session s) into hbf.
    #pragma unroll
    for (int it = 0; it < 8; ++it) {
      int idx = (it << 8) + tid;
      int t = idx >> 5, j4 = idx & 31;
      float4 a = ra[it], c = rb[it];
      union { __hip_bfloat162 b; unsigned u; } p01, p23;
      p01.b = __float22bfloat162_rn(make_float2(fmaxf(a.x, c.x), fmaxf(a.y, c.y)));
      p23.b = __float22bfloat162_rn(make_float2(fmaxf(a.z, c.z), fmaxf(a.w, c.w)));
      uint2 st; st.x = p01.u; st.y = p23.u;
      *(uint2*)&hbf[t * RS + (j4 << 2)] = st;
    }
    __syncthreads();  // B(a): hbf ready

    // Issue session s+1 staging loads (latency hidden under MFMA + s_g).
    if (s + 1 < SPB) {
      const float4* pa = (const float4*)(intra + (size_t)start_nxt * HDIM);
      const float4* pb = (const float4*)(inter + (size_t)start_nxt * HDIM);
      int nc = (n_nxt > 64) ? 64 : n_nxt;
      #pragma unroll
      for (int it = 0; it < 8; ++it) {
        int idx = (it << 8) + tid;
        int t = idx >> 5;
        float4 va = {0.f, 0.f, 0.f, 0.f}, vb = {0.f, 0.f, 0.f, 0.f};
        if (t < nc) { va = pa[idx]; vb = pb[idx]; }
        ra[it] = va; rb[it] = vb;
      }
    }
    // scalar prefetch for session s+2
    int n_n2 = 0, st_n2 = 0;
    if (s + 2 < SPB && sid0 + s + 2 < B) { n_n2 = seq[sid0 + s + 2]; st_n2 = offs[sid0 + s + 2]; }

    // D = hidden @ W2^T + c; fused sigmoid + q-dot -> alphaPart (per wave, no atomics).
    float c0 = cbuf[s][n0], c1 = cbuf[s][n1];
    #pragma unroll
    for (int mt = 0; mt < 4; ++mt) {
      floatv4 a0 = {c0, c0, c0, c0}, a1 = {c1, c1, c1, c1};
      const unsigned short* arow = &hbf[((mt << 4) + lcol) * RS + (quad << 3)];
      #pragma unroll
      for (int kt = 0; kt < 4; ++kt) {
        short8 af = *(const short8*)(arow + (kt << 5));
        a0 = __builtin_amdgcn_mfma_f32_16x16x32_bf16(af, w2f[0][kt], a0, 0, 0, 0);
        a1 = __builtin_amdgcn_mfma_f32_16x16x32_bf16(af, w2f[1][kt], a1, 0, 0, 0);
      }
      #pragma unroll
      for (int r = 0; r < 4; ++r) {
        float v = q0 * __builtin_amdgcn_rcpf(1.f + __expf(-a0[r]))
                + q1 * __builtin_amdgcn_rcpf(1.f + __expf(-a1[r]));
        v += __shfl_xor(v, 1, 64);
        v += __shfl_xor(v, 2, 64);
        v += __shfl_xor(v, 4, 64);
        v += __shfl_xor(v, 8, 64);
        if (lcol == 0) alphaPart[wid][(mt << 4) + (quad << 2) + r] = v;
      }
    }
    __syncthreads();  // B(b): alphaPart ready

    // s_g: vectorized b128 reads, alpha folded from 4 wave-partials + qb.
    {
      int jg = tid & 15, ts = tid >> 4;
      float ac[8];
      #pragma unroll
      for (int e = 0; e < 8; ++e) ac[e] = 0.f;
      #pragma unroll
      for (int tt = 0; tt < 4; ++tt) {
        int t = (tt << 4) + ts;
        float al = sq + alphaPart[0][t] + alphaPart[1][t] + alphaPart[2][t] + alphaPart[3][t];
        uint4 u = *(const uint4*)&hbf[t * RS + (jg << 3)];
        ac[0] += al * blo(u.x); ac[1] += al * bhi(u.x);
        ac[2] += al * blo(u.y); ac[3] += al * bhi(u.y);
        ac[4] += al * blo(u.z); ac[5] += al * bhi(u.z);
        ac[6] += al * blo(u.w); ac[7] += al * bhi(u.w);
      }
      #pragma unroll
      for (int e = 0; e < 8; ++e) {
        ac[e] += __shfl_xor(ac[e], 16, 64);
        ac[e] += __shfl_xor(ac[e], 32, 64);
      }
      if (quad == 0) {
        float4 s0; s0.x = ac[0]; s0.y = ac[1]; s0.z = ac[2]; s0.w = ac[3];
        float4 s1; s1.x = ac[4]; s1.y = ac[5]; s1.z = ac[6]; s1.w = ac[7];
        *(float4*)&sgpart[wid][(jg << 3)] = s0;
        *(float4*)&sgpart[wid][(jg << 3) + 4] = s1;
      }
    }
    __syncthreads();  // B(c): sgpart ready, hbf fully consumed

    if (tid < HDIM) {
      float sgv = sgpart[0][tid] + sgpart[1][tid] + sgpart[2][tid] + sgpart[3][tid];
      X[s * XS + HDIM + tid] = f2bf(sgv);
    }
    n_nxt = n_n2; start_nxt = st_n2;
  }
  __syncthreads();  // X sg-halves ready

  // ---- Batched W3 epilogue: Out = [Vn | Sg] @ W3^T + b3 (16x256x128 tile) ----
  {
    floatv4 o0 = {0.f, 0.f, 0.f, 0.f}, o1 = {0.f, 0.f, 0.f, 0.f};
    #pragma unroll
    for (int kt = 0; kt < 8; ++kt) {
      short8 af = *(const short8*)&X[lcol * XS + (kt << 5) + (quad << 3)];
      short8 bf0 = *(const short8*)(w3b + n0 * 256 + (kt << 5) + (quad << 3));
      short8 bf1 = *(const short8*)(w3b + n1 * 256 + (kt << 5) + (quad << 3));
      o0 = __builtin_amdgcn_mfma_f32_16x16x32_bf16(af, bf0, o0, 0, 0, 0);
      o1 = __builtin_amdgcn_mfma_f32_16x16x32_bf16(af, bf1, o1, 0, 0, 0);
    }
    if (quad < 2) {
      float b30 = b3[n0], b31 = b3[n1];
      #pragma unroll
      for (int r = 0; r < 4; ++r) {
        int m = (quad << 2) + r;       // session index 0..7
        int sid = sid0 + m;
        if (sid < B) {
          out[(size_t)sid * HDIM + n0] = o0[r] + b30;
          out[(size_t)sid * HDIM + n1] = o1[r] + b31;
        }
      }
    }
  }
}

extern "C" void kernel_launch(void* const* d_in, const int* in_sizes, int n_in,
                              void* d_out, int out_size, void* d_ws, size_t ws_size,
                              hipStream_t stream) {
  const float* intra = (const float*)d_in[0];
  const float* inter = (const float*)d_in[1];
  const float* W1 = (const float*)d_in[2];
  const float* b1 = (const float*)d_in[3];
  const float* W2 = (const float*)d_in[4];
  const float* b2 = (const float*)d_in[5];
  const float* qw = (const float*)d_in[6];
  const float* qb = (const float*)d_in[7];
  const float* W3 = (const float*)d_in[8];
  const float* b3 = (const float*)d_in[9];
  const int* seq = (const int*)d_in[10];
  const int B = in_sizes[10];
  float* out = (float*)d_out;

  char* ws = (char*)d_ws;
  size_t o1 = (((size_t)B * 4) + 255) & ~(size_t)255;  // after offsets
  int* offs = (int*)ws;
  unsigned short* w1b = (unsigned short*)(ws + o1);            // 32 KB
  unsigned short* w2b = (unsigned short*)(ws + o1 + 32768);    // 32 KB
  unsigned short* w3b = (unsigned short*)(ws + o1 + 65536);    // 64 KB

  hipLaunchKernelGGL(prep_kernel, dim3(129), dim3(256), 0, stream,
                     seq, offs, B, W1, W2, W3, w1b, w2b, w3b);
  int nblk = (B + SPB - 1) / SPB;
  hipLaunchKernelGGL(session_kernel, dim3(nblk), dim3(256), 0, stream,
                     intra, inter, w1b, b1, w2b, b2, qw, qb, w3b, b3, seq, offs, out, B);
}